// Round 15
// baseline (849.336 us; speedup 1.0000x reference)
//
#include <hip/hip_runtime.h>

typedef unsigned long long ull;
typedef __attribute__((ext_vector_type(8))) short bf16x8;
typedef __attribute__((ext_vector_type(4))) float f32x4;

// ---------- helpers ----------
__device__ __forceinline__ unsigned short bf16b(float x){
    unsigned u = __float_as_uint(x);
    unsigned r = (u + 0x7FFFu + ((u >> 16) & 1u)) >> 16;
    return (unsigned short)r;
}
__device__ __forceinline__ float b2f(unsigned short u){
    return __uint_as_float(((unsigned)u) << 16);
}
__device__ __forceinline__ void st4(unsigned short* p, f32x4 v){
    ull pk = (ull)bf16b(v[0]) | (((ull)bf16b(v[1])) << 16)
           | (((ull)bf16b(v[2])) << 32) | (((ull)bf16b(v[3])) << 48);
    *(ull*)p = pk;
}
__device__ __forceinline__ f32x4 ld4(const unsigned short* p){
    ull pk = *(const ull*)p;
    f32x4 v;
    v[0] = b2f((unsigned short)pk);
    v[1] = b2f((unsigned short)(pk >> 16));
    v[2] = b2f((unsigned short)(pk >> 32));
    v[3] = b2f((unsigned short)(pk >> 48));
    return v;
}

// u64 DPP reductions (max for FPS, min for KNN). All-lane valid, row_mask 0xF safe.
#define DPPMAX(k, ctrl) do { \
    unsigned _lo = (unsigned)(k), _hi = (unsigned)((k) >> 32); \
    unsigned _l2 = (unsigned)__builtin_amdgcn_update_dpp((int)_lo, (int)_lo, (ctrl), 0xF, 0xF, false); \
    unsigned _h2 = (unsigned)__builtin_amdgcn_update_dpp((int)_hi, (int)_hi, (ctrl), 0xF, 0xF, false); \
    ull _k2 = (((ull)_h2) << 32) | _l2; \
    if (_k2 > (k)) (k) = _k2; \
} while (0)
#define DPPMIN(k, ctrl) do { \
    unsigned _lo = (unsigned)(k), _hi = (unsigned)((k) >> 32); \
    unsigned _l2 = (unsigned)__builtin_amdgcn_update_dpp((int)_lo, (int)_lo, (ctrl), 0xF, 0xF, false); \
    unsigned _h2 = (unsigned)__builtin_amdgcn_update_dpp((int)_hi, (int)_hi, (ctrl), 0xF, 0xF, false); \
    ull _k2 = (((ull)_h2) << 32) | _l2; \
    if (_k2 < (k)) (k) = _k2; \
} while (0)
// ctrl codes: quad_perm(1,0,3,2)=0xB1, quad_perm(2,3,0,1)=0x4E,
// row_half_mirror=0x141, row_mirror=0x140, row_bcast15=0x142, row_bcast31=0x143

// XOR-swizzled LDS layout for row-major [rows][K*?] bf16 tiles, K-width = KT*32.
template<int KT>
__device__ __forceinline__ int swz(int r, int c){
    return r * (KT * 32) + ((((c >> 3) + r) & (KT * 4 - 1)) << 3) + (c & 7);
}

template<int KT>
__device__ __forceinline__ void gemmT(const unsigned short* __restrict__ Wt,
                                      const unsigned short* __restrict__ Blds,
                                      int ch0, int lane, f32x4 acc[4][4])
{
    int i = lane & 15, q = lane >> 4;
#pragma unroll
    for (int kt = 0; kt < KT; kt++){
        int k0 = kt * 32 + q * 8;
        bf16x8 bfr[4], afr[4];
#pragma unroll
        for (int nt = 0; nt < 4; nt++)
            bfr[nt] = *(const bf16x8*)(Blds + swz<KT>(nt * 16 + i, k0));
#pragma unroll
        for (int mt = 0; mt < 4; mt++)
            afr[mt] = *(const bf16x8*)(Wt + (size_t)(ch0 + mt * 16 + i) * (KT * 32) + k0);
#pragma unroll
        for (int mt = 0; mt < 4; mt++)
#pragma unroll
            for (int nt = 0; nt < 4; nt++)
                acc[mt][nt] = __builtin_amdgcn_mfma_f32_16x16x32_bf16(afr[mt], bfr[nt], acc[mt][nt], 0, 0, 0);
    }
}

#define ZERO44(A) do { _Pragma("unroll") for (int _m = 0; _m < 4; _m++) \
    { _Pragma("unroll") for (int _n = 0; _n < 4; _n++) { A[_m][_n][0]=0.f;A[_m][_n][1]=0.f;A[_m][_n][2]=0.f;A[_m][_n][3]=0.f; } } } while(0)

#define CTRL_AUX   (8 << 4)

// SYSTEM-scope atomics: cross-XCD polls MUST use these — agent-scope loads can be
// served stale by the consumer XCD's own L2 (r10: 21 ms poll stall).
__device__ __forceinline__ int ald_sys(const int* p){
    return __hip_atomic_load(p, __ATOMIC_RELAXED, __HIP_MEMORY_SCOPE_SYSTEM);
}
__device__ __forceinline__ void ast_sys(int* p, int v){
    __hip_atomic_store(p, v, __ATOMIC_RELAXED, __HIP_MEMORY_SCOPE_SYSTEM);
}

// ---------- KNN for one group (256-thread sub-block), register-resident ----------
__device__ __forceinline__ void knn_one(int t2, int G, float qx, float qy, float qz,
        const float* __restrict__ xyz,
        int* __restrict__ knn_idx, ull* kslot /* [2][4] parity-buffered */)
{
    int b = G >> 10;
    int lane = t2 & 63, wvi = t2 >> 6;
    float qq = qx * qx + qy * qy + qz * qz;
    unsigned fb[16];
#pragma unroll
    for (int j = 0; j < 16; j++){
        int p = t2 + (j << 8);
        const float* s = xyz + ((size_t)b * 4096 + p) * 3;
        float x = s[0], y = s[1], z = s[2];
        float d2 = qq - 2.f * (qx * x + qy * y + qz * z) + (x * x + y * y + z * z);
        unsigned bb = __float_as_uint(d2);
        fb[j] = (bb & 0x80000000u) ? ~bb : (bb | 0x80000000u);
    }
    ull lk = ~0ull;
#pragma unroll
    for (int j = 0; j < 16; j++){
        ull key = (((ull)fb[j]) << 32) | (unsigned)(t2 + (j << 8));
        if (key < lk) lk = key;
    }
    int par = 0;
    for (int r = 0; r < 16; r++){
        ull k = lk;
        DPPMIN(k, 0xB1); DPPMIN(k, 0x4E); DPPMIN(k, 0x141);
        DPPMIN(k, 0x140); DPPMIN(k, 0x142); DPPMIN(k, 0x143);
        if (lane == 63) kslot[par * 4 + wvi] = k;
        __syncthreads();
        ull s0 = kslot[par * 4 + 0], s1 = kslot[par * 4 + 1];
        ull s2 = kslot[par * 4 + 2], s3 = kslot[par * 4 + 3];
        ull ga = s0 < s1 ? s0 : s1;
        ull gb = s2 < s3 ? s2 : s3;
        ull g  = ga < gb ? ga : gb;
        int p = (int)(unsigned)g;
        if (t2 == (p & 255)){
            knn_idx[(size_t)G * 16 + r] = p;
            int jw = p >> 8;
            lk = ~0ull;
#pragma unroll
            for (int j = 0; j < 16; j++){
                if (j == jw) fb[j] = 0xFFFFFFFFu;
                ull key = (((ull)fb[j]) << 32) | (unsigned)(t2 + (j << 8));
                if (key < lk) lk = key;
            }
        }
        par ^= 1;
    }
}

// ---------- fused attention for one 4-group unit (256-thread sub-block) ----------
__device__ void attn_unit(int t, char* base, int G0, const float* nxL4,
    const unsigned short* __restrict__ pts16,
    const float* __restrict__ xyz,
    const int* __restrict__ knn_idx, const float* __restrict__ qbuf,
    const unsigned short* __restrict__ wkT, const unsigned short* __restrict__ wvT,
    const unsigned short* __restrict__ dw2T, const unsigned short* __restrict__ gw1T,
    const unsigned short* __restrict__ gw2T,
    const float* __restrict__ dw1, const float* __restrict__ db1,
    const float* __restrict__ db2, const float* __restrict__ gb1, const float* __restrict__ gb2,
    unsigned short* __restrict__ resY)
{
    unsigned short* bufA = (unsigned short*)base;            // 32KB
    unsigned short* bufU = (unsigned short*)(base + 32768);  // 32KB
    int lane = t & 63, wave = t >> 6;
    int i = lane & 15, q = lane >> 4;
    int ch0 = wave * 64;
    unsigned short* ptsA = bufU;
    float* dw1s  = (float*)(bufU + 8192);
    float* db1s  = (float*)(bufU + 9728);
    float* xyznS = (float*)(bufU + 10240);
    int*   idxs  = (int*)  (bufU + 10624);

    if (t < 64) idxs[t] = knn_idx[G0 * 16 + t];
    dw1s[t] = dw1[t]; dw1s[256 + t] = dw1[256 + t]; dw1s[512 + t] = dw1[512 + t];
    db1s[t] = db1[t];
    __syncthreads();

    if (t < 64){
        int G = G0 + (t >> 4); int bb = G >> 10; int p = idxs[t];
        const float* xp = xyz + ((size_t)bb * 4096 + p) * 3;
        const float* nz = nxL4 + (t >> 4) * 3;
        xyznS[t * 3 + 0] = xp[0] - nz[0];
        xyznS[t * 3 + 1] = xp[1] - nz[1];
        xyznS[t * 3 + 2] = xp[2] - nz[2];
    }
    {
        int r = t >> 2, seg = t & 3;
        int G = G0 + (r >> 4); int bb = G >> 10; int p = idxs[r];
        const uint4* src = (const uint4*)(pts16 + ((size_t)bb * 4096 + p) * 128 + seg * 32);
#pragma unroll
        for (int j = 0; j < 4; j++){
            uint4 v = src[j];
            *(uint4*)(ptsA + swz<4>(r, seg * 32 + j * 8)) = v;
        }
    }
    __syncthreads();

    {   // pos1 = relu(xyzn @ dw1 + db1)
        int r = lane;
        int o0 = wave * 64;
        float x = xyznS[r * 3], y = xyznS[r * 3 + 1], z = xyznS[r * 3 + 2];
#pragma unroll
        for (int j = 0; j < 64; j += 4){
            int o = o0 + j;
            f32x4 v;
#pragma unroll
            for (int e = 0; e < 4; e++)
                v[e] = fmaxf(db1s[o + e] + x * dw1s[o + e] + y * dw1s[256 + o + e] + z * dw1s[512 + o + e], 0.f);
            st4(bufA + swz<8>(r, o), v);
        }
    }
    __syncthreads();

    f32x4 accP[4][4]; ZERO44(accP);
    gemmT<8>(dw2T, bufA, ch0, lane, accP);
#pragma unroll
    for (int mt = 0; mt < 4; mt++){
        f32x4 d2v = *(const f32x4*)(db2 + ch0 + mt * 16 + q * 4);
#pragma unroll
        for (int nt = 0; nt < 4; nt++) accP[mt][nt] += d2v;
    }
    f32x4 accK[4][4]; ZERO44(accK);
    gemmT<4>(wkT, ptsA, ch0, lane, accK);
    __syncthreads();

#pragma unroll
    for (int mt = 0; mt < 4; mt++){
        int c = ch0 + mt * 16 + q * 4;
#pragma unroll
        for (int nt = 0; nt < 4; nt++){
            int r = nt * 16 + i;
            f32x4 qv = *(const f32x4*)(qbuf + (size_t)(G0 + nt) * 256 + c);
            f32x4 tv = qv - accK[mt][nt] + accP[mt][nt];
            st4(bufA + swz<8>(r, c), tv);
        }
    }
    f32x4 accV[4][4]; ZERO44(accV);
    gemmT<4>(wvT, ptsA, ch0, lane, accV);
    __syncthreads();

#pragma unroll
    for (int mt = 0; mt < 4; mt++){
        int c = ch0 + mt * 16 + q * 4;
#pragma unroll
        for (int nt = 0; nt < 4; nt++){
            int r = nt * 16 + i;
            f32x4 uv = accV[mt][nt] + accP[mt][nt];
            st4(bufU + swz<8>(r, c), uv);
        }
    }
    f32x4 acc1[4][4]; ZERO44(acc1);
    gemmT<8>(gw1T, bufA, ch0, lane, acc1);
    __syncthreads();

#pragma unroll
    for (int mt = 0; mt < 4; mt++){
        int c = ch0 + mt * 16 + q * 4;
        f32x4 g1v = *(const f32x4*)(gb1 + c);
#pragma unroll
        for (int nt = 0; nt < 4; nt++){
            int r = nt * 16 + i;
            f32x4 av = acc1[mt][nt] + g1v;
#pragma unroll
            for (int e = 0; e < 4; e++) av[e] = fmaxf(av[e], 0.f);
            st4(bufA + swz<8>(r, c), av);
        }
    }
    __syncthreads();

    f32x4 acc2[4][4]; ZERO44(acc2);
    gemmT<8>(gw2T, bufA, ch0, lane, acc2);
    __syncthreads();

#pragma unroll
    for (int mt = 0; mt < 4; mt++){
        int c = ch0 + mt * 16 + q * 4;
        f32x4 g2v = *(const f32x4*)(gb2 + c);
#pragma unroll
        for (int nt = 0; nt < 4; nt++){
            int r = nt * 16 + i;
            f32x4 ev;
#pragma unroll
            for (int e = 0; e < 4; e++) ev[e] = __expf((acc2[mt][nt][e] + g2v[e]) * 0.0625f);
            st4(bufA + swz<8>(r, c), ev);
        }
    }
    __syncthreads();

    {
        int g = t >> 6, c4 = (t & 63) * 4;
        f32x4 num; num[0]=0.f;num[1]=0.f;num[2]=0.f;num[3]=0.f;
        f32x4 den = num;
#pragma unroll
        for (int rr = 0; rr < 16; rr++){
            int r = g * 16 + rr;
            f32x4 e4 = ld4(bufA + swz<8>(r, c4));
            f32x4 u4 = ld4(bufU + swz<8>(r, c4));
            num += e4 * u4;
            den += e4;
        }
        f32x4 rv = num / den;
        st4(resY + (size_t)(G0 + g) * 256 + c4, rv);
    }
}

// ---------- one chunk = 8 groups. Entry: dataflow poll (SYSTEM-scope loads) ----------
__device__ void do_chunk(int t, int c, char* SM,
    const float* __restrict__ xyz, const float* __restrict__ nxyz,
    const float* __restrict__ points, const float* __restrict__ wqT,
    const int* __restrict__ fps_idx, int* __restrict__ knn_idx, float* __restrict__ qbuf,
    const unsigned short* __restrict__ pts16,
    const unsigned short* __restrict__ wkT, const unsigned short* __restrict__ wvT,
    const unsigned short* __restrict__ dw2T, const unsigned short* __restrict__ gw1T,
    const unsigned short* __restrict__ gw2T,
    const float* __restrict__ dw1, const float* __restrict__ db1,
    const float* __restrict__ db2, const float* __restrict__ gb1, const float* __restrict__ gb2,
    unsigned short* __restrict__ resY)
{
    int g0 = c * 8;
    int sub = t >> 8, t2 = t & 255;
    ull*   kslot = (ull*)(SM + 131072) + sub * 8;   // [2][4] parity per sub
    int*   fpsL  = (int*)  (SM + 131200);           // 8 ints
    float* nxL   = (float*)(SM + 131232);           // 24 floats
    // --- dataflow gate: poll published values directly (coherent-point loads) ---
    if (t < 64){
        for (;;){
            int v = 0; bool ok = true;
            if (t < 8){
                v = ald_sys(fps_idx + g0 + t); ok = (v != -1);
            } else if (t < 32){
                v = ald_sys((const int*)nxyz + (size_t)g0 * 3 + (t - 8)); ok = (v != (int)0xFFFFFFFF);
            }
            if (__ballot(ok) == ~0ull){
                if (t < 8) fpsL[t] = v;
                else if (t < 32) ((int*)nxL)[t - 8] = v;
                break;
            }
            __builtin_amdgcn_s_sleep(8);
        }
    }
    __syncthreads();
    // --- KNN: subs handle even/odd groups of the chunk (register-resident selection) ---
    for (int r4 = 0; r4 < 4; r4++){
        int gl = r4 * 2 + sub;
        knn_one(t2, g0 + gl, nxL[gl * 3], nxL[gl * 3 + 1], nxL[gl * 3 + 2],
                xyz, knn_idx, kslot);
    }
    __syncthreads();
    // --- Q for the chunk ---
    {
        float* sp = (float*)SM;   // [8][128]
        if (t < 256){
            int r = t >> 5, c4 = (t & 31) * 4;
            int G = g0 + r; int b = G >> 10; int p = fpsL[r];
            *(f32x4*)(sp + r * 128 + c4) = *(const f32x4*)(points + ((size_t)b * 4096 + p) * 128 + c4);
        }
        __syncthreads();
        float acc[4] = {0.f, 0.f, 0.f, 0.f};
        const float* wr = wqT + t2 * 128;
        for (int k = 0; k < 128; k += 4){
            f32x4 w = *(const f32x4*)(wr + k);
#pragma unroll
            for (int r = 0; r < 4; r++){
                const float* row = sp + (sub * 4 + r) * 128;
                acc[r] += w[0]*row[k] + w[1]*row[k+1] + w[2]*row[k+2] + w[3]*row[k+3];
            }
        }
#pragma unroll
        for (int r = 0; r < 4; r++) qbuf[(size_t)(g0 + sub * 4 + r) * 256 + t2] = acc[r];
        __syncthreads();
    }
    // --- ATTN: 2 units side by side (64KB LDS each) ---
    attn_unit(t2, SM + sub * 65536, g0 + sub * 4, nxL + sub * 12, pts16, xyz, knn_idx, qbuf,
              wkT, wvT, dw2T, gw1T, gw2T, dw1, db1, db2, gb1, gb2, resY);
    __syncthreads();
}

// ---------- init: ctrl zero + sentinels in fps_idx / nxyz ----------
__global__ __launch_bounds__(256) void init_ws(int* __restrict__ ctrl,
                                               int* __restrict__ fps_idx,
                                               int* __restrict__ nxyz_i)
{
    int i = blockIdx.x * 256 + threadIdx.x;
    if (i < 256) ctrl[i] = 0;
    if (i < 8192) fps_idx[i] = -1;
    if (i < 24576) nxyz_i[i] = (int)0xFFFFFFFF;
}

// ---------- mega kernel: 256 blocks x 512 thr, all resident (1 block/CU) ----------
// r11 structure; ONLY change: FPS per-step barrier is raw s_barrier + lgkmcnt(0)
// (no vmcnt drain) so the fire-and-forget system-scope publish stores stay in
// flight across barriers instead of stalling wave 7 ~1-2us at the next step.
__global__ __launch_bounds__(512, 2) void mega(
    const float* __restrict__ xyz, float* __restrict__ nxyz_out, int* __restrict__ fps_idx,
    const float* __restrict__ pts, unsigned short* __restrict__ pts16,
    const float* __restrict__ wq, const float* __restrict__ wk, const float* __restrict__ wv,
    const float* __restrict__ dw2, const float* __restrict__ gw1, const float* __restrict__ gw2,
    const float* __restrict__ lw,
    float* __restrict__ wqT, unsigned short* __restrict__ wkT, unsigned short* __restrict__ wvT,
    unsigned short* __restrict__ dw2T, unsigned short* __restrict__ gw1T,
    unsigned short* __restrict__ gw2T, unsigned short* __restrict__ lwT,
    float* __restrict__ stats,
    const float* __restrict__ dw1, const float* __restrict__ db1, const float* __restrict__ db2,
    const float* __restrict__ gb1, const float* __restrict__ gb2,
    int* __restrict__ knn_idx, float* __restrict__ qbuf, unsigned short* __restrict__ resY,
    int* __restrict__ ctrl)
{
    __shared__ __align__(16) char SM[132096];
    int blk = blockIdx.x, t = threadIdx.x;

    if (blk < 8){
        // ---- FPS ----
        int b = blk;
        int lane = t & 63, wvi = t >> 6;
        float* sx = (float*)SM;
        float* sy = (float*)(SM + 16384);
        float* sz = (float*)(SM + 32768);
        ull (*slotK)[8] = (ull(*)[8])(SM + 53248);
        for (int p = t; p < 4096; p += 512){
            const float* s = xyz + ((size_t)b * 4096 + p) * 3;
            sx[p] = s[0]; sy[p] = s[1]; sz[p] = s[2];
        }
        __syncthreads();
        float px[8], py[8], pz[8], dist[8];
        unsigned nplo[8];
#pragma unroll
        for (int j = 0; j < 8; j++){
            int p = t + (j << 9);
            px[j] = sx[p]; py[j] = sy[p]; pz[j] = sz[p];
            dist[j] = 1e10f;
            nplo[j] = ~(unsigned)p;
            asm volatile("" : "+v"(px[j]), "+v"(py[j]), "+v"(pz[j]), "+v"(nplo[j]));
        }
        // publish metadata (wave 7): lane<16 -> fps_idx of step s0+lane;
        // lanes 16..63 -> coord d of step s0+myStep
        int myStep = 99, myD = 0;
        int* pubp = nullptr;
        if (wvi == 7){
            if (lane < 16){
                myStep = lane;
                pubp = fps_idx + b * 1024 + lane;
            } else {
                int idx = lane - 16;
                myStep = idx / 3; myD = idx - myStep * 3;
                pubp = (int*)nxyz_out + (size_t)b * 3072 + myStep * 3 + myD;
            }
        }
        unsigned hv = 0;
        int far = 0;
        float cx = sx[0], cy = sy[0], cz = sz[0];
        int par = 0;
        for (int s = 0; s < 1024; s++){
            if (wvi == 7 && (s & 15) == myStep)
                hv = (lane < 16) ? (unsigned)far
                                 : __float_as_uint(myD == 0 ? cx : (myD == 1 ? cy : cz));
            ull lb = 0;
#pragma unroll
            for (int j = 0; j < 8; j++){
                float dx = __fsub_rn(px[j], cx);
                float dy = __fsub_rn(py[j], cy);
                float dz = __fsub_rn(pz[j], cz);
                float d = __fadd_rn(__fadd_rn(__fmul_rn(dx, dx), __fmul_rn(dy, dy)), __fmul_rn(dz, dz));
                float nd = fminf(dist[j], d);
                dist[j] = nd;
                ull k2 = (((ull)__float_as_uint(nd)) << 32) | nplo[j];
                if (k2 > lb) lb = k2;
            }
            DPPMAX(lb, 0xB1); DPPMAX(lb, 0x4E); DPPMAX(lb, 0x141);
            DPPMAX(lb, 0x140); DPPMAX(lb, 0x142); DPPMAX(lb, 0x143);
            if (lane == 63) slotK[par][wvi] = lb;
            // barrier WITHOUT vmcnt drain: LDS ordering only (publish stores float)
            asm volatile("s_waitcnt lgkmcnt(0)\n\ts_barrier" ::: "memory");
            ull k = slotK[par][lane & 7];
            DPPMAX(k, 0xB1); DPPMAX(k, 0x4E); DPPMAX(k, 0x141);
            far = (int)(~(unsigned)k);
            cx = sx[far]; cy = sy[far]; cz = sz[far];
            if (wvi == 7 && (s & 15) == 15){
                ast_sys(pubp, (int)hv);
                pubp += 16 * ((lane < 16) ? 1 : 3);
            }
            par ^= 1;
        }
        // tail chunk of own batch (steps 1016..1023; published above, polled in do_chunk)
        if (t == 0){ while (ald_sys(ctrl + CTRL_AUX) < 248) __builtin_amdgcn_s_sleep(16); }
        __syncthreads();
        __threadfence();
        do_chunk(t, b * 128 + 127, SM, xyz, nxyz_out, pts, wqT, fps_idx, knn_idx, qbuf,
                 pts16, wkT, wvT, dw2T, gw1T, gw2T, dw1, db1, db2, gb1, gb2, resY);
        return;
    }

    // ---- worker ----
    int w = blk - 8;
    // aux: weight transposes / bf16 (704 slices), points->bf16 (2048 slices), stats zero
    for (int base = w; base < 704; base += 248){
        if (base == 0) stats[t & 511] = 0.f;
        int i = base * 512 + t;
        if (i < 32768){ int n = i >> 7, kk = i & 127; wqT[i] = wq[kk * 256 + n]; }
        else if (i < 65536){ int j = i - 32768; int n = j >> 7, kk = j & 127; wkT[j] = bf16b(wk[kk * 256 + n]); }
        else if (i < 98304){ int j = i - 65536; int n = j >> 7, kk = j & 127; wvT[j] = bf16b(wv[kk * 256 + n]); }
        else if (i < 163840){ int j = i - 98304; int n = j >> 8, kk = j & 255; dw2T[j] = bf16b(dw2[kk * 256 + n]); }
        else if (i < 229376){ int j = i - 163840; int n = j >> 8, kk = j & 255; gw1T[j] = bf16b(gw1[kk * 256 + n]); }
        else if (i < 294912){ int j = i - 229376; int n = j >> 8, kk = j & 255; gw2T[j] = bf16b(gw2[kk * 256 + n]); }
        else { int j = i - 294912; int n = j >> 8, kk = j & 255; lwT[j] = bf16b(lw[kk * 256 + n]); }
    }
    for (int base = w; base < 2048; base += 248){
        int i = (base * 512 + t) * 4;
        f32x4 v = *(const f32x4*)(pts + i);
        ull pk = (ull)bf16b(v[0]) | (((ull)bf16b(v[1])) << 16)
               | (((ull)bf16b(v[2])) << 32) | (((ull)bf16b(v[3])) << 48);
        *(ull*)(pts16 + i) = pk;
    }
    __threadfence();
    __syncthreads();
    if (t == 0){
        atomicAdd(ctrl + CTRL_AUX, 1);
        while (ald_sys(ctrl + CTRL_AUX) < 248) __builtin_amdgcn_s_sleep(16);
    }
    __syncthreads();
    __threadfence();
    // chunks ordered by readiness: p = cc*8 + b  (cc 0..126, b 0..7); gating inside do_chunk
    for (int j = 0; j < 5; j++){
        int p = w + 248 * j;
        if (p >= 1016) break;
        int bb = p & 7, cc = p >> 3;
        do_chunk(t, bb * 128 + cc, SM, xyz, nxyz_out, pts, wqT, fps_idx, knn_idx, qbuf,
                 pts16, wkT, wvT, dw2T, gw1T, gw2T, dw1, db1, db2, gb1, gb2, resY);
    }
}

// ---------- kernel 5: z = res @ lw + lb, + channel stats ----------
__global__ __launch_bounds__(256, 2) void z_gemm(const unsigned short* __restrict__ resY,
                                                 const unsigned short* __restrict__ lwT,
                                                 const float* __restrict__ lb,
                                                 float* __restrict__ zbuf,
                                                 float* __restrict__ stats)
{
    int t = threadIdx.x, lane = t & 63, wave = t >> 6;
    int i = lane & 15, q = lane >> 4;
    int row0 = blockIdx.x * 128;
    int ch0 = wave * 64;
    f32x4 acc[4][8];
#pragma unroll
    for (int mt = 0; mt < 4; mt++)
#pragma unroll
        for (int nt = 0; nt < 8; nt++){ acc[mt][nt][0]=0.f;acc[mt][nt][1]=0.f;acc[mt][nt][2]=0.f;acc[mt][nt][3]=0.f; }
#pragma unroll
    for (int kt = 0; kt < 8; kt++){
        int k0 = kt * 32 + q * 8;
        bf16x8 a[4], bb[8];
#pragma unroll
        for (int mt = 0; mt < 4; mt++)
            a[mt] = *(const bf16x8*)(lwT + (size_t)(ch0 + mt * 16 + i) * 256 + k0);
#pragma unroll
        for (int nt = 0; nt < 8; nt++)
            bb[nt] = *(const bf16x8*)(resY + (size_t)(row0 + nt * 16 + i) * 256 + k0);
#pragma unroll
        for (int mt = 0; mt < 4; mt++)
#pragma unroll
            for (int nt = 0; nt < 8; nt++)
                acc[mt][nt] = __builtin_amdgcn_mfma_f32_16x16x32_bf16(a[mt], bb[nt], acc[mt][nt], 0, 0, 0);
    }
    f32x4 s1[4], s2[4];
#pragma unroll
    for (int mt = 0; mt < 4; mt++){ s1[mt][0]=0.f;s1[mt][1]=0.f;s1[mt][2]=0.f;s1[mt][3]=0.f; s2[mt]=s1[mt]; }
#pragma unroll
    for (int mt = 0; mt < 4; mt++){
        int c = ch0 + mt * 16 + q * 4;
        f32x4 lb4 = *(const f32x4*)(lb + c);
#pragma unroll
        for (int nt = 0; nt < 8; nt++){
            int r = row0 + nt * 16 + i;
            f32x4 z = acc[mt][nt] + lb4;
            *(f32x4*)(zbuf + (size_t)r * 256 + c) = z;
            s1[mt] += z;
            s2[mt] += z * z;
        }
    }
    for (int m = 1; m < 16; m <<= 1){
#pragma unroll
        for (int mt = 0; mt < 4; mt++)
#pragma unroll
            for (int e = 0; e < 4; e++){
                s1[mt][e] += __shfl_xor(s1[mt][e], m);
                s2[mt][e] += __shfl_xor(s2[mt][e], m);
            }
    }
    if (i == 0){
#pragma unroll
        for (int mt = 0; mt < 4; mt++){
            int c = ch0 + mt * 16 + q * 4;
#pragma unroll
            for (int e = 0; e < 4; e++){
                atomicAdd(&stats[c + e], s1[mt][e]);
                atomicAdd(&stats[256 + c + e], s2[mt][e]);
            }
        }
    }
}

// ---------- kernel 6: BN (batch stats) + ReLU, vectorized f32x4 ----------
__global__ __launch_bounds__(256) void bn_kernel(const float* __restrict__ zbuf,
                                                 const float* __restrict__ stats,
                                                 const float* __restrict__ bn_g,
                                                 const float* __restrict__ bn_b,
                                                 float* __restrict__ out)
{
    int idx = blockIdx.x * 256 + threadIdx.x;    // 2048 blocks x 256 thr x 4 floats
    int e4 = idx * 4;
    int c4 = e4 & 255;
    f32x4 s1 = *(const f32x4*)(stats + c4);
    f32x4 s2 = *(const f32x4*)(stats + 256 + c4);
    f32x4 gg = *(const f32x4*)(bn_g + c4);
    f32x4 bb = *(const f32x4*)(bn_b + c4);
    f32x4 z = *(const f32x4*)(zbuf + e4);
    f32x4 y;
#pragma unroll
    for (int e = 0; e < 4; e++){
        float mean = s1[e] * (1.f / 8192.f);
        float var = s2[e] * (1.f / 8192.f) - mean * mean;
        float inv = rsqrtf(var + 1e-5f);
        y[e] = fmaxf(gg[e] * (z[e] - mean) * inv + bb[e], 0.f);
    }
    *(f32x4*)(out + 24576 + e4) = y;
}

// ---------- launch ----------
extern "C" void kernel_launch(void* const* d_in, const int* in_sizes, int n_in,
                              void* d_out, int out_size, void* d_ws, size_t ws_size,
                              hipStream_t stream)
{
    const float* xyz    = (const float*)d_in[0];
    const float* points = (const float*)d_in[1];
    const float* wq  = (const float*)d_in[2];
    const float* wk  = (const float*)d_in[3];
    const float* wv  = (const float*)d_in[4];
    const float* dw1 = (const float*)d_in[5];
    const float* db1 = (const float*)d_in[6];
    const float* dw2 = (const float*)d_in[7];
    const float* db2 = (const float*)d_in[8];
    const float* gw1 = (const float*)d_in[9];
    const float* gb1 = (const float*)d_in[10];
    const float* gw2 = (const float*)d_in[11];
    const float* gb2 = (const float*)d_in[12];
    const float* lw  = (const float*)d_in[13];
    const float* lb  = (const float*)d_in[14];
    const float* bn_g = (const float*)d_in[15];
    const float* bn_b = (const float*)d_in[16];
    float* out = (float*)d_out;

    char* ws = (char*)d_ws;
    int*            fps_idx = (int*)(ws + 0);
    int*            knn_idx = (int*)(ws + 32768);
    float*          qbuf    = (float*)(ws + 557056);
    unsigned short* pts16   = (unsigned short*)(ws + 8945664);
    unsigned short* wkT     = (unsigned short*)(ws + 17334272);
    unsigned short* wvT     = (unsigned short*)(ws + 17399808);
    unsigned short* dw2T    = (unsigned short*)(ws + 17465344);
    unsigned short* gw1T    = (unsigned short*)(ws + 17596416);
    unsigned short* gw2T    = (unsigned short*)(ws + 17727488);
    unsigned short* lwT     = (unsigned short*)(ws + 17858560);
    float*          wqT     = (float*)(ws + 17989632);
    unsigned short* resY    = (unsigned short*)(ws + 18120704);
    float*          zbuf    = (float*)(ws + 22315008);
    float*          stats   = (float*)(ws + 30703616);
    // ctrl lives in zbuf's first 1KB: dead during mega, overwritten by z_gemm later
    int*            ctrl    = (int*)(ws + 22315008);

    init_ws<<<96, 256, 0, stream>>>(ctrl, fps_idx, (int*)out);
    mega<<<256, 512, 0, stream>>>(xyz, out, fps_idx, points, pts16,
                                  wq, wk, wv, dw2, gw1, gw2, lw,
                                  wqT, wkT, wvT, dw2T, gw1T, gw2T, lwT, stats,
                                  dw1, db1, db2, gb1, gb2,
                                  knn_idx, qbuf, resY, ctrl);
    z_gemm<<<64, 256, 0, stream>>>(resY, lwT, lb, zbuf, stats);
    bn_kernel<<<2048, 256, 0, stream>>>(zbuf, stats, bn_g, bn_b, out);
}

// Round 16
// 845.357 us; speedup vs baseline: 1.0047x; 1.0047x over previous
//
#include <hip/hip_runtime.h>

typedef unsigned long long ull;
typedef __attribute__((ext_vector_type(8))) short bf16x8;
typedef __attribute__((ext_vector_type(4))) float f32x4;

// ---------- helpers ----------
__device__ __forceinline__ unsigned short bf16b(float x){
    unsigned u = __float_as_uint(x);
    unsigned r = (u + 0x7FFFu + ((u >> 16) & 1u)) >> 16;
    return (unsigned short)r;
}
__device__ __forceinline__ float b2f(unsigned short u){
    return __uint_as_float(((unsigned)u) << 16);
}
__device__ __forceinline__ void st4(unsigned short* p, f32x4 v){
    ull pk = (ull)bf16b(v[0]) | (((ull)bf16b(v[1])) << 16)
           | (((ull)bf16b(v[2])) << 32) | (((ull)bf16b(v[3])) << 48);
    *(ull*)p = pk;
}
__device__ __forceinline__ f32x4 ld4(const unsigned short* p){
    ull pk = *(const ull*)p;
    f32x4 v;
    v[0] = b2f((unsigned short)pk);
    v[1] = b2f((unsigned short)(pk >> 16));
    v[2] = b2f((unsigned short)(pk >> 32));
    v[3] = b2f((unsigned short)(pk >> 48));
    return v;
}

// u64 DPP reductions (max for FPS, min for KNN). All-lane valid, row_mask 0xF safe.
#define DPPMAX(k, ctrl) do { \
    unsigned _lo = (unsigned)(k), _hi = (unsigned)((k) >> 32); \
    unsigned _l2 = (unsigned)__builtin_amdgcn_update_dpp((int)_lo, (int)_lo, (ctrl), 0xF, 0xF, false); \
    unsigned _h2 = (unsigned)__builtin_amdgcn_update_dpp((int)_hi, (int)_hi, (ctrl), 0xF, 0xF, false); \
    ull _k2 = (((ull)_h2) << 32) | _l2; \
    if (_k2 > (k)) (k) = _k2; \
} while (0)
#define DPPMIN(k, ctrl) do { \
    unsigned _lo = (unsigned)(k), _hi = (unsigned)((k) >> 32); \
    unsigned _l2 = (unsigned)__builtin_amdgcn_update_dpp((int)_lo, (int)_lo, (ctrl), 0xF, 0xF, false); \
    unsigned _h2 = (unsigned)__builtin_amdgcn_update_dpp((int)_hi, (int)_hi, (ctrl), 0xF, 0xF, false); \
    ull _k2 = (((ull)_h2) << 32) | _l2; \
    if (_k2 < (k)) (k) = _k2; \
} while (0)
// ctrl codes: quad_perm(1,0,3,2)=0xB1, quad_perm(2,3,0,1)=0x4E,
// row_half_mirror=0x141, row_mirror=0x140, row_bcast15=0x142, row_bcast31=0x143

// XOR-swizzled LDS layout for row-major [rows][K*?] bf16 tiles, K-width = KT*32.
template<int KT>
__device__ __forceinline__ int swz(int r, int c){
    return r * (KT * 32) + ((((c >> 3) + r) & (KT * 4 - 1)) << 3) + (c & 7);
}

template<int KT>
__device__ __forceinline__ void gemmT(const unsigned short* __restrict__ Wt,
                                      const unsigned short* __restrict__ Blds,
                                      int ch0, int lane, f32x4 acc[4][4])
{
    int i = lane & 15, q = lane >> 4;
#pragma unroll
    for (int kt = 0; kt < KT; kt++){
        int k0 = kt * 32 + q * 8;
        bf16x8 bfr[4], afr[4];
#pragma unroll
        for (int nt = 0; nt < 4; nt++)
            bfr[nt] = *(const bf16x8*)(Blds + swz<KT>(nt * 16 + i, k0));
#pragma unroll
        for (int mt = 0; mt < 4; mt++)
            afr[mt] = *(const bf16x8*)(Wt + (size_t)(ch0 + mt * 16 + i) * (KT * 32) + k0);
#pragma unroll
        for (int mt = 0; mt < 4; mt++)
#pragma unroll
            for (int nt = 0; nt < 4; nt++)
                acc[mt][nt] = __builtin_amdgcn_mfma_f32_16x16x32_bf16(afr[mt], bfr[nt], acc[mt][nt], 0, 0, 0);
    }
}

#define ZERO44(A) do { _Pragma("unroll") for (int _m = 0; _m < 4; _m++) \
    { _Pragma("unroll") for (int _n = 0; _n < 4; _n++) { A[_m][_n][0]=0.f;A[_m][_n][1]=0.f;A[_m][_n][2]=0.f;A[_m][_n][3]=0.f; } } } while(0)

#define CTRL_AUX   (8 << 4)

// SYSTEM-scope atomics: cross-XCD polls MUST use these — agent-scope loads can be
// served stale by the consumer XCD's own L2 (r10: 21 ms poll stall).
__device__ __forceinline__ int ald_sys(const int* p){
    return __hip_atomic_load(p, __ATOMIC_RELAXED, __HIP_MEMORY_SCOPE_SYSTEM);
}
__device__ __forceinline__ void ast_sys(int* p, int v){
    __hip_atomic_store(p, v, __ATOMIC_RELAXED, __HIP_MEMORY_SCOPE_SYSTEM);
}

// ---------- KNN for one group (256-thread sub-block), register-resident ----------
__device__ __forceinline__ void knn_one(int t2, int G, float qx, float qy, float qz,
        const float* __restrict__ xyz,
        int* __restrict__ knn_idx, ull* kslot /* [2][4] parity-buffered */)
{
    int b = G >> 10;
    int lane = t2 & 63, wvi = t2 >> 6;
    float qq = qx * qx + qy * qy + qz * qz;
    unsigned fb[16];
#pragma unroll
    for (int j = 0; j < 16; j++){
        int p = t2 + (j << 8);
        const float* s = xyz + ((size_t)b * 4096 + p) * 3;
        float x = s[0], y = s[1], z = s[2];
        float d2 = qq - 2.f * (qx * x + qy * y + qz * z) + (x * x + y * y + z * z);
        unsigned bb = __float_as_uint(d2);
        fb[j] = (bb & 0x80000000u) ? ~bb : (bb | 0x80000000u);
    }
    ull lk = ~0ull;
#pragma unroll
    for (int j = 0; j < 16; j++){
        ull key = (((ull)fb[j]) << 32) | (unsigned)(t2 + (j << 8));
        if (key < lk) lk = key;
    }
    int par = 0;
    for (int r = 0; r < 16; r++){
        ull k = lk;
        DPPMIN(k, 0xB1); DPPMIN(k, 0x4E); DPPMIN(k, 0x141);
        DPPMIN(k, 0x140); DPPMIN(k, 0x142); DPPMIN(k, 0x143);
        if (lane == 63) kslot[par * 4 + wvi] = k;
        __syncthreads();
        ull s0 = kslot[par * 4 + 0], s1 = kslot[par * 4 + 1];
        ull s2 = kslot[par * 4 + 2], s3 = kslot[par * 4 + 3];
        ull ga = s0 < s1 ? s0 : s1;
        ull gb = s2 < s3 ? s2 : s3;
        ull g  = ga < gb ? ga : gb;
        int p = (int)(unsigned)g;
        if (t2 == (p & 255)){
            knn_idx[(size_t)G * 16 + r] = p;
            int jw = p >> 8;
            lk = ~0ull;
#pragma unroll
            for (int j = 0; j < 16; j++){
                if (j == jw) fb[j] = 0xFFFFFFFFu;
                ull key = (((ull)fb[j]) << 32) | (unsigned)(t2 + (j << 8));
                if (key < lk) lk = key;
            }
        }
        par ^= 1;
    }
}

// ---------- fused attention for one 4-group unit (256-thread sub-block) ----------
__device__ void attn_unit(int t, char* base, int G0, const float* nxL4,
    const unsigned short* __restrict__ pts16,
    const float* __restrict__ xyz,
    const int* __restrict__ knn_idx, const float* __restrict__ qbuf,
    const unsigned short* __restrict__ wkT, const unsigned short* __restrict__ wvT,
    const unsigned short* __restrict__ dw2T, const unsigned short* __restrict__ gw1T,
    const unsigned short* __restrict__ gw2T,
    const float* __restrict__ dw1, const float* __restrict__ db1,
    const float* __restrict__ db2, const float* __restrict__ gb1, const float* __restrict__ gb2,
    unsigned short* __restrict__ resY)
{
    unsigned short* bufA = (unsigned short*)base;            // 32KB
    unsigned short* bufU = (unsigned short*)(base + 32768);  // 32KB
    int lane = t & 63, wave = t >> 6;
    int i = lane & 15, q = lane >> 4;
    int ch0 = wave * 64;
    unsigned short* ptsA = bufU;
    float* dw1s  = (float*)(bufU + 8192);
    float* db1s  = (float*)(bufU + 9728);
    float* xyznS = (float*)(bufU + 10240);
    int*   idxs  = (int*)  (bufU + 10624);

    if (t < 64) idxs[t] = knn_idx[G0 * 16 + t];
    dw1s[t] = dw1[t]; dw1s[256 + t] = dw1[256 + t]; dw1s[512 + t] = dw1[512 + t];
    db1s[t] = db1[t];
    __syncthreads();

    if (t < 64){
        int G = G0 + (t >> 4); int bb = G >> 10; int p = idxs[t];
        const float* xp = xyz + ((size_t)bb * 4096 + p) * 3;
        const float* nz = nxL4 + (t >> 4) * 3;
        xyznS[t * 3 + 0] = xp[0] - nz[0];
        xyznS[t * 3 + 1] = xp[1] - nz[1];
        xyznS[t * 3 + 2] = xp[2] - nz[2];
    }
    {
        int r = t >> 2, seg = t & 3;
        int G = G0 + (r >> 4); int bb = G >> 10; int p = idxs[r];
        const uint4* src = (const uint4*)(pts16 + ((size_t)bb * 4096 + p) * 128 + seg * 32);
#pragma unroll
        for (int j = 0; j < 4; j++){
            uint4 v = src[j];
            *(uint4*)(ptsA + swz<4>(r, seg * 32 + j * 8)) = v;
        }
    }
    __syncthreads();

    {   // pos1 = relu(xyzn @ dw1 + db1)
        int r = lane;
        int o0 = wave * 64;
        float x = xyznS[r * 3], y = xyznS[r * 3 + 1], z = xyznS[r * 3 + 2];
#pragma unroll
        for (int j = 0; j < 64; j += 4){
            int o = o0 + j;
            f32x4 v;
#pragma unroll
            for (int e = 0; e < 4; e++)
                v[e] = fmaxf(db1s[o + e] + x * dw1s[o + e] + y * dw1s[256 + o + e] + z * dw1s[512 + o + e], 0.f);
            st4(bufA + swz<8>(r, o), v);
        }
    }
    __syncthreads();

    f32x4 accP[4][4]; ZERO44(accP);
    gemmT<8>(dw2T, bufA, ch0, lane, accP);
#pragma unroll
    for (int mt = 0; mt < 4; mt++){
        f32x4 d2v = *(const f32x4*)(db2 + ch0 + mt * 16 + q * 4);
#pragma unroll
        for (int nt = 0; nt < 4; nt++) accP[mt][nt] += d2v;
    }
    f32x4 accK[4][4]; ZERO44(accK);
    gemmT<4>(wkT, ptsA, ch0, lane, accK);
    __syncthreads();

#pragma unroll
    for (int mt = 0; mt < 4; mt++){
        int c = ch0 + mt * 16 + q * 4;
#pragma unroll
        for (int nt = 0; nt < 4; nt++){
            int r = nt * 16 + i;
            f32x4 qv = *(const f32x4*)(qbuf + (size_t)(G0 + nt) * 256 + c);
            f32x4 tv = qv - accK[mt][nt] + accP[mt][nt];
            st4(bufA + swz<8>(r, c), tv);
        }
    }
    f32x4 accV[4][4]; ZERO44(accV);
    gemmT<4>(wvT, ptsA, ch0, lane, accV);
    __syncthreads();

#pragma unroll
    for (int mt = 0; mt < 4; mt++){
        int c = ch0 + mt * 16 + q * 4;
#pragma unroll
        for (int nt = 0; nt < 4; nt++){
            int r = nt * 16 + i;
            f32x4 uv = accV[mt][nt] + accP[mt][nt];
            st4(bufU + swz<8>(r, c), uv);
        }
    }
    f32x4 acc1[4][4]; ZERO44(acc1);
    gemmT<8>(gw1T, bufA, ch0, lane, acc1);
    __syncthreads();

#pragma unroll
    for (int mt = 0; mt < 4; mt++){
        int c = ch0 + mt * 16 + q * 4;
        f32x4 g1v = *(const f32x4*)(gb1 + c);
#pragma unroll
        for (int nt = 0; nt < 4; nt++){
            int r = nt * 16 + i;
            f32x4 av = acc1[mt][nt] + g1v;
#pragma unroll
            for (int e = 0; e < 4; e++) av[e] = fmaxf(av[e], 0.f);
            st4(bufA + swz<8>(r, c), av);
        }
    }
    __syncthreads();

    f32x4 acc2[4][4]; ZERO44(acc2);
    gemmT<8>(gw2T, bufA, ch0, lane, acc2);
    __syncthreads();

#pragma unroll
    for (int mt = 0; mt < 4; mt++){
        int c = ch0 + mt * 16 + q * 4;
        f32x4 g2v = *(const f32x4*)(gb2 + c);
#pragma unroll
        for (int nt = 0; nt < 4; nt++){
            int r = nt * 16 + i;
            f32x4 ev;
#pragma unroll
            for (int e = 0; e < 4; e++) ev[e] = __expf((acc2[mt][nt][e] + g2v[e]) * 0.0625f);
            st4(bufA + swz<8>(r, c), ev);
        }
    }
    __syncthreads();

    {
        int g = t >> 6, c4 = (t & 63) * 4;
        f32x4 num; num[0]=0.f;num[1]=0.f;num[2]=0.f;num[3]=0.f;
        f32x4 den = num;
#pragma unroll
        for (int rr = 0; rr < 16; rr++){
            int r = g * 16 + rr;
            f32x4 e4 = ld4(bufA + swz<8>(r, c4));
            f32x4 u4 = ld4(bufU + swz<8>(r, c4));
            num += e4 * u4;
            den += e4;
        }
        f32x4 rv = num / den;
        st4(resY + (size_t)(G0 + g) * 256 + c4, rv);
    }
}

// ---------- one chunk = 8 groups. Entry: dataflow poll (SYSTEM-scope loads) ----------
__device__ void do_chunk(int t, int c, char* SM,
    const float* __restrict__ xyz, const float* __restrict__ nxyz,
    const float* __restrict__ points, const float* __restrict__ wqT,
    const int* __restrict__ fps_idx, int* __restrict__ knn_idx, float* __restrict__ qbuf,
    const unsigned short* __restrict__ pts16,
    const unsigned short* __restrict__ wkT, const unsigned short* __restrict__ wvT,
    const unsigned short* __restrict__ dw2T, const unsigned short* __restrict__ gw1T,
    const unsigned short* __restrict__ gw2T,
    const float* __restrict__ dw1, const float* __restrict__ db1,
    const float* __restrict__ db2, const float* __restrict__ gb1, const float* __restrict__ gb2,
    unsigned short* __restrict__ resY)
{
    int g0 = c * 8;
    int sub = t >> 8, t2 = t & 255;
    ull*   kslot = (ull*)(SM + 131072) + sub * 8;   // [2][4] parity per sub
    int*   fpsL  = (int*)  (SM + 131200);           // 8 ints
    float* nxL   = (float*)(SM + 131232);           // 24 floats
    // --- dataflow gate: poll published values directly (coherent-point loads) ---
    if (t < 64){
        for (;;){
            int v = 0; bool ok = true;
            if (t < 8){
                v = ald_sys(fps_idx + g0 + t); ok = (v != -1);
            } else if (t < 32){
                v = ald_sys((const int*)nxyz + (size_t)g0 * 3 + (t - 8)); ok = (v != (int)0xFFFFFFFF);
            }
            if (__ballot(ok) == ~0ull){
                if (t < 8) fpsL[t] = v;
                else if (t < 32) ((int*)nxL)[t - 8] = v;
                break;
            }
            __builtin_amdgcn_s_sleep(8);
        }
    }
    __syncthreads();
    // --- KNN: subs handle even/odd groups of the chunk (register-resident selection) ---
    for (int r4 = 0; r4 < 4; r4++){
        int gl = r4 * 2 + sub;
        knn_one(t2, g0 + gl, nxL[gl * 3], nxL[gl * 3 + 1], nxL[gl * 3 + 2],
                xyz, knn_idx, kslot);
    }
    __syncthreads();
    // --- Q for the chunk ---
    {
        float* sp = (float*)SM;   // [8][128]
        if (t < 256){
            int r = t >> 5, c4 = (t & 31) * 4;
            int G = g0 + r; int b = G >> 10; int p = fpsL[r];
            *(f32x4*)(sp + r * 128 + c4) = *(const f32x4*)(points + ((size_t)b * 4096 + p) * 128 + c4);
        }
        __syncthreads();
        float acc[4] = {0.f, 0.f, 0.f, 0.f};
        const float* wr = wqT + t2 * 128;
        for (int k = 0; k < 128; k += 4){
            f32x4 w = *(const f32x4*)(wr + k);
#pragma unroll
            for (int r = 0; r < 4; r++){
                const float* row = sp + (sub * 4 + r) * 128;
                acc[r] += w[0]*row[k] + w[1]*row[k+1] + w[2]*row[k+2] + w[3]*row[k+3];
            }
        }
#pragma unroll
        for (int r = 0; r < 4; r++) qbuf[(size_t)(g0 + sub * 4 + r) * 256 + t2] = acc[r];
        __syncthreads();
    }
    // --- ATTN: 2 units side by side (64KB LDS each) ---
    attn_unit(t2, SM + sub * 65536, g0 + sub * 4, nxL + sub * 12, pts16, xyz, knn_idx, qbuf,
              wkT, wvT, dw2T, gw1T, gw2T, dw1, db1, db2, gb1, gb2, resY);
    __syncthreads();
}

// ---------- init: ctrl zero + sentinels in fps_idx / nxyz ----------
__global__ __launch_bounds__(256) void init_ws(int* __restrict__ ctrl,
                                               int* __restrict__ fps_idx,
                                               int* __restrict__ nxyz_i)
{
    int i = blockIdx.x * 256 + threadIdx.x;
    if (i < 256) ctrl[i] = 0;
    if (i < 8192) fps_idx[i] = -1;
    if (i < 24576) nxyz_i[i] = (int)0xFFFFFFFF;
}

// ---------- mega kernel: 256 blocks x 512 thr, all resident (1 block/CU) ----------
// (r11-proven structure, verbatim)
__global__ __launch_bounds__(512, 2) void mega(
    const float* __restrict__ xyz, float* __restrict__ nxyz_out, int* __restrict__ fps_idx,
    const float* __restrict__ pts, unsigned short* __restrict__ pts16,
    const float* __restrict__ wq, const float* __restrict__ wk, const float* __restrict__ wv,
    const float* __restrict__ dw2, const float* __restrict__ gw1, const float* __restrict__ gw2,
    const float* __restrict__ lw,
    float* __restrict__ wqT, unsigned short* __restrict__ wkT, unsigned short* __restrict__ wvT,
    unsigned short* __restrict__ dw2T, unsigned short* __restrict__ gw1T,
    unsigned short* __restrict__ gw2T, unsigned short* __restrict__ lwT,
    float* __restrict__ stats,
    const float* __restrict__ dw1, const float* __restrict__ db1, const float* __restrict__ db2,
    const float* __restrict__ gb1, const float* __restrict__ gb2,
    int* __restrict__ knn_idx, float* __restrict__ qbuf, unsigned short* __restrict__ resY,
    int* __restrict__ ctrl)
{
    __shared__ __align__(16) char SM[132096];
    int blk = blockIdx.x, t = threadIdx.x;

    if (blk < 8){
        // ---- FPS ----
        int b = blk;
        int lane = t & 63, wvi = t >> 6;
        float* sx = (float*)SM;
        float* sy = (float*)(SM + 16384);
        float* sz = (float*)(SM + 32768);
        ull (*slotK)[8] = (ull(*)[8])(SM + 53248);
        for (int p = t; p < 4096; p += 512){
            const float* s = xyz + ((size_t)b * 4096 + p) * 3;
            sx[p] = s[0]; sy[p] = s[1]; sz[p] = s[2];
        }
        __syncthreads();
        float px[8], py[8], pz[8], dist[8];
        unsigned nplo[8];
#pragma unroll
        for (int j = 0; j < 8; j++){
            int p = t + (j << 9);
            px[j] = sx[p]; py[j] = sy[p]; pz[j] = sz[p];
            dist[j] = 1e10f;
            nplo[j] = ~(unsigned)p;
            asm volatile("" : "+v"(px[j]), "+v"(py[j]), "+v"(pz[j]), "+v"(nplo[j]));
        }
        // publish metadata (wave 7): lane<16 -> fps_idx of step s0+lane;
        // lanes 16..63 -> coord d of step s0+myStep
        int myStep = 99, myD = 0;
        int* pubp = nullptr;
        if (wvi == 7){
            if (lane < 16){
                myStep = lane;
                pubp = fps_idx + b * 1024 + lane;
            } else {
                int idx = lane - 16;
                myStep = idx / 3; myD = idx - myStep * 3;
                pubp = (int*)nxyz_out + (size_t)b * 3072 + myStep * 3 + myD;
            }
        }
        unsigned hv = 0;
        int far = 0;
        float cx = sx[0], cy = sy[0], cz = sz[0];
        int par = 0;
        for (int s = 0; s < 1024; s++){
            if (wvi == 7 && (s & 15) == myStep)
                hv = (lane < 16) ? (unsigned)far
                                 : __float_as_uint(myD == 0 ? cx : (myD == 1 ? cy : cz));
            ull lb = 0;
#pragma unroll
            for (int j = 0; j < 8; j++){
                float dx = __fsub_rn(px[j], cx);
                float dy = __fsub_rn(py[j], cy);
                float dz = __fsub_rn(pz[j], cz);
                float d = __fadd_rn(__fadd_rn(__fmul_rn(dx, dx), __fmul_rn(dy, dy)), __fmul_rn(dz, dz));
                float nd = fminf(dist[j], d);
                dist[j] = nd;
                ull k2 = (((ull)__float_as_uint(nd)) << 32) | nplo[j];
                if (k2 > lb) lb = k2;
            }
            DPPMAX(lb, 0xB1); DPPMAX(lb, 0x4E); DPPMAX(lb, 0x141);
            DPPMAX(lb, 0x140); DPPMAX(lb, 0x142); DPPMAX(lb, 0x143);
            if (lane == 63) slotK[par][wvi] = lb;
            __syncthreads();
            ull k = slotK[par][lane & 7];
            DPPMAX(k, 0xB1); DPPMAX(k, 0x4E); DPPMAX(k, 0x141);
            far = (int)(~(unsigned)k);
            cx = sx[far]; cy = sy[far]; cz = sz[far];
            if (wvi == 7 && (s & 15) == 15){
                ast_sys(pubp, (int)hv);
                pubp += 16 * ((lane < 16) ? 1 : 3);
            }
            par ^= 1;
        }
        // tail chunk of own batch (steps 1016..1023; published above, polled in do_chunk)
        if (t == 0){ while (ald_sys(ctrl + CTRL_AUX) < 248) __builtin_amdgcn_s_sleep(16); }
        __syncthreads();
        __threadfence();
        do_chunk(t, b * 128 + 127, SM, xyz, nxyz_out, pts, wqT, fps_idx, knn_idx, qbuf,
                 pts16, wkT, wvT, dw2T, gw1T, gw2T, dw1, db1, db2, gb1, gb2, resY);
        return;
    }

    // ---- worker ----
    int w = blk - 8;
    // aux: weight transposes / bf16 (704 slices), points->bf16 (2048 slices), stats zero
    for (int base = w; base < 704; base += 248){
        if (base == 0) stats[t & 511] = 0.f;
        int i = base * 512 + t;
        if (i < 32768){ int n = i >> 7, kk = i & 127; wqT[i] = wq[kk * 256 + n]; }
        else if (i < 65536){ int j = i - 32768; int n = j >> 7, kk = j & 127; wkT[j] = bf16b(wk[kk * 256 + n]); }
        else if (i < 98304){ int j = i - 65536; int n = j >> 7, kk = j & 127; wvT[j] = bf16b(wv[kk * 256 + n]); }
        else if (i < 163840){ int j = i - 98304; int n = j >> 8, kk = j & 255; dw2T[j] = bf16b(dw2[kk * 256 + n]); }
        else if (i < 229376){ int j = i - 163840; int n = j >> 8, kk = j & 255; gw1T[j] = bf16b(gw1[kk * 256 + n]); }
        else if (i < 294912){ int j = i - 229376; int n = j >> 8, kk = j & 255; gw2T[j] = bf16b(gw2[kk * 256 + n]); }
        else { int j = i - 294912; int n = j >> 8, kk = j & 255; lwT[j] = bf16b(lw[kk * 256 + n]); }
    }
    for (int base = w; base < 2048; base += 248){
        int i = (base * 512 + t) * 4;
        f32x4 v = *(const f32x4*)(pts + i);
        ull pk = (ull)bf16b(v[0]) | (((ull)bf16b(v[1])) << 16)
               | (((ull)bf16b(v[2])) << 32) | (((ull)bf16b(v[3])) << 48);
        *(ull*)(pts16 + i) = pk;
    }
    __threadfence();
    __syncthreads();
    if (t == 0){
        atomicAdd(ctrl + CTRL_AUX, 1);
        while (ald_sys(ctrl + CTRL_AUX) < 248) __builtin_amdgcn_s_sleep(16);
    }
    __syncthreads();
    __threadfence();
    // chunks ordered by readiness: p = cc*8 + b  (cc 0..126, b 0..7); gating inside do_chunk
    for (int j = 0; j < 5; j++){
        int p = w + 248 * j;
        if (p >= 1016) break;
        int bb = p & 7, cc = p >> 3;
        do_chunk(t, bb * 128 + cc, SM, xyz, nxyz_out, pts, wqT, fps_idx, knn_idx, qbuf,
                 pts16, wkT, wvT, dw2T, gw1T, gw2T, dw1, db1, db2, gb1, gb2, resY);
    }
}

// ---------- kernel 5: z = res @ lw + lb, + channel stats ----------
__global__ __launch_bounds__(256, 2) void z_gemm(const unsigned short* __restrict__ resY,
                                                 const unsigned short* __restrict__ lwT,
                                                 const float* __restrict__ lb,
                                                 float* __restrict__ zbuf,
                                                 float* __restrict__ stats)
{
    int t = threadIdx.x, lane = t & 63, wave = t >> 6;
    int i = lane & 15, q = lane >> 4;
    int row0 = blockIdx.x * 128;
    int ch0 = wave * 64;
    f32x4 acc[4][8];
#pragma unroll
    for (int mt = 0; mt < 4; mt++)
#pragma unroll
        for (int nt = 0; nt < 8; nt++){ acc[mt][nt][0]=0.f;acc[mt][nt][1]=0.f;acc[mt][nt][2]=0.f;acc[mt][nt][3]=0.f; }
#pragma unroll
    for (int kt = 0; kt < 8; kt++){
        int k0 = kt * 32 + q * 8;
        bf16x8 a[4], bb[8];
#pragma unroll
        for (int mt = 0; mt < 4; mt++)
            a[mt] = *(const bf16x8*)(lwT + (size_t)(ch0 + mt * 16 + i) * 256 + k0);
#pragma unroll
        for (int nt = 0; nt < 8; nt++)
            bb[nt] = *(const bf16x8*)(resY + (size_t)(row0 + nt * 16 + i) * 256 + k0);
#pragma unroll
        for (int mt = 0; mt < 4; mt++)
#pragma unroll
            for (int nt = 0; nt < 8; nt++)
                acc[mt][nt] = __builtin_amdgcn_mfma_f32_16x16x32_bf16(a[mt], bb[nt], acc[mt][nt], 0, 0, 0);
    }
    f32x4 s1[4], s2[4];
#pragma unroll
    for (int mt = 0; mt < 4; mt++){ s1[mt][0]=0.f;s1[mt][1]=0.f;s1[mt][2]=0.f;s1[mt][3]=0.f; s2[mt]=s1[mt]; }
#pragma unroll
    for (int mt = 0; mt < 4; mt++){
        int c = ch0 + mt * 16 + q * 4;
        f32x4 lb4 = *(const f32x4*)(lb + c);
#pragma unroll
        for (int nt = 0; nt < 8; nt++){
            int r = row0 + nt * 16 + i;
            f32x4 z = acc[mt][nt] + lb4;
            *(f32x4*)(zbuf + (size_t)r * 256 + c) = z;
            s1[mt] += z;
            s2[mt] += z * z;
        }
    }
    for (int m = 1; m < 16; m <<= 1){
#pragma unroll
        for (int mt = 0; mt < 4; mt++)
#pragma unroll
            for (int e = 0; e < 4; e++){
                s1[mt][e] += __shfl_xor(s1[mt][e], m);
                s2[mt][e] += __shfl_xor(s2[mt][e], m);
            }
    }
    if (i == 0){
#pragma unroll
        for (int mt = 0; mt < 4; mt++){
            int c = ch0 + mt * 16 + q * 4;
#pragma unroll
            for (int e = 0; e < 4; e++){
                atomicAdd(&stats[c + e], s1[mt][e]);
                atomicAdd(&stats[256 + c + e], s2[mt][e]);
            }
        }
    }
}

// ---------- kernel 6: BN (batch stats) + ReLU, vectorized f32x4 ----------
__global__ __launch_bounds__(256) void bn_kernel(const float* __restrict__ zbuf,
                                                 const float* __restrict__ stats,
                                                 const float* __restrict__ bn_g,
                                                 const float* __restrict__ bn_b,
                                                 float* __restrict__ out)
{
    int idx = blockIdx.x * 256 + threadIdx.x;    // 2048 blocks x 256 thr x 4 floats
    int e4 = idx * 4;
    int c4 = e4 & 255;
    f32x4 s1 = *(const f32x4*)(stats + c4);
    f32x4 s2 = *(const f32x4*)(stats + 256 + c4);
    f32x4 gg = *(const f32x4*)(bn_g + c4);
    f32x4 bb = *(const f32x4*)(bn_b + c4);
    f32x4 z = *(const f32x4*)(zbuf + e4);
    f32x4 y;
#pragma unroll
    for (int e = 0; e < 4; e++){
        float mean = s1[e] * (1.f / 8192.f);
        float var = s2[e] * (1.f / 8192.f) - mean * mean;
        float inv = rsqrtf(var + 1e-5f);
        y[e] = fmaxf(gg[e] * (z[e] - mean) * inv + bb[e], 0.f);
    }
    *(f32x4*)(out + 24576 + e4) = y;
}

// ---------- launch ----------
extern "C" void kernel_launch(void* const* d_in, const int* in_sizes, int n_in,
                              void* d_out, int out_size, void* d_ws, size_t ws_size,
                              hipStream_t stream)
{
    const float* xyz    = (const float*)d_in[0];
    const float* points = (const float*)d_in[1];
    const float* wq  = (const float*)d_in[2];
    const float* wk  = (const float*)d_in[3];
    const float* wv  = (const float*)d_in[4];
    const float* dw1 = (const float*)d_in[5];
    const float* db1 = (const float*)d_in[6];
    const float* dw2 = (const float*)d_in[7];
    const float* db2 = (const float*)d_in[8];
    const float* gw1 = (const float*)d_in[9];
    const float* gb1 = (const float*)d_in[10];
    const float* gw2 = (const float*)d_in[11];
    const float* gb2 = (const float*)d_in[12];
    const float* lw  = (const float*)d_in[13];
    const float* lb  = (const float*)d_in[14];
    const float* bn_g = (const float*)d_in[15];
    const float* bn_b = (const float*)d_in[16];
    float* out = (float*)d_out;

    char* ws = (char*)d_ws;
    int*            fps_idx = (int*)(ws + 0);
    int*            knn_idx = (int*)(ws + 32768);
    float*          qbuf    = (float*)(ws + 557056);
    unsigned short* pts16   = (unsigned short*)(ws + 8945664);
    unsigned short* wkT     = (unsigned short*)(ws + 17334272);
    unsigned short* wvT     = (unsigned short*)(ws + 17399808);
    unsigned short* dw2T    = (unsigned short*)(ws + 17465344);
    unsigned short* gw1T    = (unsigned short*)(ws + 17596416);
    unsigned short* gw2T    = (unsigned short*)(ws + 17727488);
    unsigned short* lwT     = (unsigned short*)(ws + 17858560);
    float*          wqT     = (float*)(ws + 17989632);
    unsigned short* resY    = (unsigned short*)(ws + 18120704);
    float*          zbuf    = (float*)(ws + 22315008);
    float*          stats   = (float*)(ws + 30703616);
    // ctrl lives in zbuf's first 1KB: dead during mega, overwritten by z_gemm later
    int*            ctrl    = (int*)(ws + 22315008);

    init_ws<<<96, 256, 0, stream>>>(ctrl, fps_idx, (int*)out);
    mega<<<256, 512, 0, stream>>>(xyz, out, fps_idx, points, pts16,
                                  wq, wk, wv, dw2, gw1, gw2, lw,
                                  wqT, wkT, wvT, dw2T, gw1T, gw2T, lwT, stats,
                                  dw1, db1, db2, gb1, gb2,
                                  knn_idx, qbuf, resY, ctrl);
    z_gemm<<<64, 256, 0, stream>>>(resY, lwT, lb, zbuf, stats);
    bn_kernel<<<2048, 256, 0, stream>>>(zbuf, stats, bn_g, bn_b, out);
}